// Round 2
// baseline (663.875 us; speedup 1.0000x reference)
//
#include <hip/hip_runtime.h>
#include <hip/hip_bf16.h>

// Problem: B=4, N=4096, D_MODEL=1024, H=16, DEPTH=64 (linear attention + LN)
// Pipeline: wtrans -> [conv->gemm]x3 (QKV; elu+1 on Q/K; fused q_sum on Q; fused Z on K)
//           -> ktq_partial -> ktq_reduce -> stagec -> gemm(Wo) -> LN
// R4: XOR-swizzled LDS + LDS-staged coalesced C store. R5: BK=64 (505 TF, MfmaUtil 18.7%).
// R6: 256^2/8-wave 4-phase K-tile schedule, counted vmcnt(6), raw s_barrier, setprio.
//     -> 690 TF, MfmaUtil 25%: frag reads and their MFMA sat in the SAME phase, so
//     LDS and matrix pipes strictly alternated (model ceiling ~30% — matched measure).
// R7: software-pipelined frag reads ONE PHASE AHEAD (m201's actual overlap mechanism):
//     phase q issues ds_reads for q+1 (q3: B+A-q0 of next tile) before MFMA(q);
//     counted lgkmcnt(4/12) drains only the PREVIOUS phase's reads, leaving the new
//     ones in flight under the MFMA cluster. Parity-indexed reg buffers (af[2], bfr[2]),
//     tk-loop unrolled x2 for compile-time indices. Barriers 8->5 per tile: pre-MFMA
//     barrier kept only at q3 (collectivizes vmcnt(6)); q0-q2 rely on end barrier+lgkm.

typedef __attribute__((ext_vector_type(8))) short short8;
typedef __attribute__((ext_vector_type(4))) float floatx4;
typedef __attribute__((ext_vector_type(4))) unsigned short ushortx4;
typedef __attribute__((ext_vector_type(8))) unsigned short ushortx8;

#define DEVINL __device__ __forceinline__

DEVINL unsigned short f2bf(float f) {
  unsigned int u = __builtin_bit_cast(unsigned int, f);
  u += 0x7fffu + ((u >> 16) & 1u);            // RNE
  return (unsigned short)(u >> 16);
}
DEVINL float bf2f(unsigned short h) {
  unsigned int u = ((unsigned int)h) << 16;
  return __builtin_bit_cast(float, u);
}
// async global->LDS, 16B per lane; LDS dest = wave-uniform base + lane*16
DEVINL void g2l16(const void* g, void* l) {
  __builtin_amdgcn_global_load_lds((const __attribute__((address_space(1))) void*)g,
                                   (__attribute__((address_space(3))) void*)l, 16, 0, 0);
}

// ---------------- fp32 -> bf16 elementwise (memory-bound) ----------------
__global__ __launch_bounds__(256) void conv_kernel(const float* __restrict__ in,
                                                   unsigned short* __restrict__ out) {
  const size_t i = ((size_t)blockIdx.x * 256 + threadIdx.x) * 8;
  const float4 a = *(const float4*)(in + i);
  const float4 b = *(const float4*)(in + i + 4);
  ushortx8 o;
  o[0] = f2bf(a.x); o[1] = f2bf(a.y); o[2] = f2bf(a.z); o[3] = f2bf(a.w);
  o[4] = f2bf(b.x); o[5] = f2bf(b.y); o[6] = f2bf(b.z); o[7] = f2bf(b.w);
  *(ushortx8*)(out + i) = o;
}

// ---------------- weight transpose + fp32->bf16 ----------------
struct W4 { const float* w[4]; };

__global__ __launch_bounds__(256) void wtrans_kernel(W4 wp, unsigned short* wt) {
  const int z = blockIdx.z;
  const float* W = wp.w[z];
  unsigned short* WT = wt + (size_t)z * 1024 * 1024;
  __shared__ float tile[32][33];
  const int bx = blockIdx.x, by = blockIdx.y;
  const int t = threadIdx.x, r = t >> 5, c = t & 31;
#pragma unroll
  for (int p = 0; p < 4; ++p)
    tile[p * 8 + r][c] = W[(size_t)(by * 32 + p * 8 + r) * 1024 + bx * 32 + c];
  __syncthreads();
#pragma unroll
  for (int p = 0; p < 4; ++p)
    WT[(size_t)(bx * 32 + p * 8 + r) * 1024 + by * 32 + c] = f2bf(tile[c][p * 8 + r]);
}

// ---------------- main GEMM: C[M,N] = A[M,K] * BT[N,K]^T + bias ----------------
// 256x256 tile, 8 waves (2m x 4n), per-wave 128x64 output, BK=64, 16 K-tiles.
// LDS: 2 buffers x (A 32KB + B 32KB) = 128KB. Swizzle: logical 8-elem col-chunk c of
// row r stored at physical chunk c ^ (r&7) (pre-swizzled global source, linear LDS dest).
// Phase q: {stage 2 g2l | [q3: vmcnt(6); barrier] | prefetch frag reads for q+1 |
//           counted lgkmcnt | setprio(1) 16 MFMA setprio(0) | barrier}.
// Staging: q0->A1,A3(t+1); q1,q2->B(t+2); q3->A0,A2(t+2). vmcnt(6) once per tile
// (vmcnt(0) only before the last tile). Reads for phase p always issued at p-1.
__global__ __launch_bounds__(512, 2) void gemm_bt_kernel(const unsigned short* __restrict__ A,
                                                         const unsigned short* __restrict__ BT,
                                                         const float* __restrict__ bias,
                                                         unsigned short* __restrict__ C,
                                                         int act, int qsflag, int zflag,
                                                         float* qsum, float* Z,
                                                         int M, int N, int K) {
  const int mb = M >> 8;
  const int id = blockIdx.x;
  const int m0 = (id % mb) << 8;
  const int n0 = (id / mb) << 8;
  __shared__ unsigned short smem[65536];   // 128 KiB; k-loop: [buf][A 16384 | B 16384]
  const int t = threadIdx.x, lane = t & 63, wave = t >> 6;
  const int wm = wave >> 2, wn = wave & 3;
  const int srow = lane >> 3;                       // 0..7 row-in-chunk (staging)
  const int scol = ((lane & 7) ^ srow) * 8;         // pre-swizzled source col-chunk
  const int rl = lane & 15, qw = lane >> 4;
  const int NT = K >> 6;                            // 16 (even; tk-loop unrolled x2)

  floatx4 acc[8][4] = {};

  const unsigned short* Ag = A + (size_t)m0 * K;
  const unsigned short* Bg = BT + (size_t)n0 * K;

#define LA(c) (smem + (c) * 32768)
#define LB(c) (smem + (c) * 32768 + 16384)

  // stage this wave's 8-row chunk of a 64-row unit [R,R+64) at k-offset k0 into tile Lt
  auto STG = [&](unsigned short* Lt, const unsigned short* Gt, int R, int k0) {
    const int r0 = R + wave * 8;                    // wave-uniform
    g2l16(Gt + (size_t)(r0 + srow) * K + (k0 + scol), (void*)(Lt + r0 * 64));
  };
  // frag-read address helper (logical k-chunk c of row r lives at chunk c ^ (r&7))
  auto FRAG = [&](const unsigned short* Lt, int row, int ks) -> short8 {
    return *(const short8*)&Lt[row * 64 + (((ks * 4 + qw) ^ (rl & 7)) * 8)];
  };

  // prologue: tile0 fully (8 loads), tile1 minus A1/A3 (6 loads)
  STG(LB(0), Bg, 0, 0);    STG(LB(0), Bg, 64, 0);
  STG(LB(0), Bg, 128, 0);  STG(LB(0), Bg, 192, 0);
  STG(LA(0), Ag, 0, 0);    STG(LA(0), Ag, 128, 0);
  STG(LA(0), Ag, 64, 0);   STG(LA(0), Ag, 192, 0);
  STG(LB(1), Bg, 0, 64);   STG(LB(1), Bg, 64, 64);
  STG(LB(1), Bg, 128, 64); STG(LB(1), Bg, 192, 64);
  STG(LA(1), Ag, 0, 64);   STG(LA(1), Ag, 128, 64);
  asm volatile("s_waitcnt vmcnt(6)" ::: "memory");  // tile0 landed; tile1 (6) in flight
  __builtin_amdgcn_s_barrier();                     // collectivize before frag reads

  // prologue frag reads: tile0 B (all) + tile0 A-quadrant0
  short8 af[2][2][2];   // [phase parity][mt][ks]
  short8 bfr[2][4][2];  // [tile parity][nt][ks]
#pragma unroll
  for (int nt = 0; nt < 4; ++nt)
#pragma unroll
    for (int ks = 0; ks < 2; ++ks)
      bfr[0][nt][ks] = FRAG(LB(0), wn * 64 + nt * 16 + rl, ks);
#pragma unroll
  for (int mt = 0; mt < 2; ++mt)
#pragma unroll
    for (int ks = 0; ks < 2; ++ks)
      af[0][mt][ks] = FRAG(LA(0), wm * 128 + mt * 16 + rl, ks);

  for (int tt = 0; tt < NT; tt += 2) {
#pragma unroll
    for (int h = 0; h < 2; ++h) {                   // tile parity: tk & 1 == h
      const int tk = tt + h;
      unsigned short* lAc = LA(h);
      unsigned short* lBc = LB(h);
      unsigned short* lAn = LA(h ^ 1);
      unsigned short* lBn = LB(h ^ 1);
#pragma unroll
      for (int q = 0; q < 4; ++q) {
        // ---- stage (regions free: readers drained >=1 barrier earlier) ----
        if (q == 0) {
          if (tk + 1 < NT) { const int k1 = (tk + 1) << 6; STG(lAn, Ag, 64, k1); STG(lAn, Ag, 192, k1); }
        } else if (q == 1) {
          if (tk + 2 < NT) { const int k2 = (tk + 2) << 6; STG(lBc, Bg, 0, k2); STG(lBc, Bg, 64, k2); }
        } else if (q == 2) {
          if (tk + 2 < NT) { const int k2 = (tk + 2) << 6; STG(lBc, Bg, 128, k2); STG(lBc, Bg, 192, k2); }
        } else {
          if (tk + 2 < NT) { const int k2 = (tk + 2) << 6; STG(lAc, Ag, 0, k2); STG(lAc, Ag, 128, k2); }
          if (tk + 1 < NT) {
            if (tk + 1 == NT - 1) asm volatile("s_waitcnt vmcnt(0)" ::: "memory");
            else                  asm volatile("s_waitcnt vmcnt(6)" ::: "memory");
          }
          __builtin_amdgcn_s_barrier();             // collectivize vmcnt before reads
        }
        // ---- prefetch frag reads for NEXT phase; drain only PREVIOUS phase ----
        if (q < 3) {
#pragma unroll
          for (int mt = 0; mt < 2; ++mt)
#pragma unroll
            for (int ks = 0; ks < 2; ++ks)
              af[(q + 1) & 1][mt][ks] = FRAG(lAc, wm * 128 + (q + 1) * 32 + mt * 16 + rl, ks);
          asm volatile("s_waitcnt lgkmcnt(4)" ::: "memory");
        } else if (tk + 1 < NT) {
#pragma unroll
          for (int nt = 0; nt < 4; ++nt)
#pragma unroll
            for (int ks = 0; ks < 2; ++ks)
              bfr[h ^ 1][nt][ks] = FRAG(lBn, wn * 64 + nt * 16 + rl, ks);
#pragma unroll
          for (int mt = 0; mt < 2; ++mt)
#pragma unroll
            for (int ks = 0; ks < 2; ++ks)
              af[0][mt][ks] = FRAG(lAn, wm * 128 + mt * 16 + rl, ks);
          asm volatile("s_waitcnt lgkmcnt(12)" ::: "memory");
        } else {
          asm volatile("s_waitcnt lgkmcnt(0)" ::: "memory");
        }
        // ---- MFMA: consumes regs loaded in phase q-1 (already drained) ----
        __builtin_amdgcn_s_setprio(1);
#pragma unroll
        for (int ks = 0; ks < 2; ++ks)
#pragma unroll
          for (int mt = 0; mt < 2; ++mt)
#pragma unroll
            for (int nt = 0; nt < 4; ++nt)
              acc[q * 2 + mt][nt] = __builtin_amdgcn_mfma_f32_16x16x32_bf16(
                  af[q & 1][mt][ks], bfr[h][nt][ks], acc[q * 2 + mt][nt], 0, 0, 0);
        __builtin_amdgcn_s_setprio(0);
        __builtin_amdgcn_s_barrier();
      }
    }
  }

  // ---- epilogue: C/D layout col=lane&15, row=(lane>>4)*4+reg ----
  // full 256x256 C tile staged in LDS (chunk ^ (row&15) swizzle), coalesced store.
  __syncthreads();   // full fence: loop LDS traffic drained before reuse
  const int bb = m0 >> 12;   // 256-row tiles never straddle a batch
  float cs[4] = {0.f, 0.f, 0.f, 0.f};
  float zacc[8][4];
#pragma unroll
  for (int mt = 0; mt < 8; ++mt)
#pragma unroll
    for (int r = 0; r < 4; ++r) zacc[mt][r] = 0.f;

#pragma unroll
  for (int nt = 0; nt < 4; ++nt) {
    const int coll = wn * 64 + nt * 16 + rl;
    const int colg = n0 + coll;
    const float bv = bias[colg];
    float qsv = 0.f;
    if (zflag) qsv = qsum[(bb * 16 + (colg >> 6)) * 64 + (colg & 63)];
    const int chnk = wn * 4 + nt;                    // 16-col chunk index
#pragma unroll
    for (int mt = 0; mt < 8; ++mt) {
#pragma unroll
      for (int r = 0; r < 4; ++r) {
        const int rowl = wm * 128 + mt * 16 + qw * 4 + r;
        float v = acc[mt][nt][r] + bv;
        if (act) v = (v > 0.f) ? (v + 1.f) : __expf(v);   // elu(x)+1
        cs[nt] += v;
        if (zflag) zacc[mt][r] += v * qsv;
        smem[rowl * 256 + ((chnk ^ (rowl & 15)) * 16) + rl] = f2bf(v);
      }
    }
  }
  __syncthreads();
  // coalesced store: 256 rows x 512B; per row 32 threads x 16B
#pragma unroll
  for (int i = 0; i < 16; ++i) {
    const int idx = i * 512 + t;
    const int row = idx >> 5;
    const int seg = idx & 31;
    const int phys = (seg >> 1) ^ (row & 15);
    *(short8*)(C + (size_t)(m0 + row) * N + n0 + seg * 8) =
        *(const short8*)&smem[row * 256 + phys * 16 + (seg & 1) * 8];
  }

  if (qsflag) {
#pragma unroll
    for (int nt = 0; nt < 4; ++nt) {
      float v = cs[nt];
      v += __shfl_xor(v, 16);
      v += __shfl_xor(v, 32);   // lanes 0..15 hold this wave's 128-row column sum
      if (lane < 16) {
        const int colg = n0 + wn * 64 + nt * 16 + lane;
        atomicAdd(&qsum[(bb * 16 + (colg >> 6)) * 64 + (colg & 63)], v);
      }
    }
  }
  if (zflag) {
    // wave wn covers ALL 64 cols of head h: reduce over lane&15 -> full Z per row
    const int h = (n0 >> 6) + wn;
#pragma unroll
    for (int mt = 0; mt < 8; ++mt) {
#pragma unroll
      for (int r = 0; r < 4; ++r) {
        float v = zacc[mt][r];
        v += __shfl_xor(v, 1); v += __shfl_xor(v, 2);
        v += __shfl_xor(v, 4); v += __shfl_xor(v, 8);
        if ((lane & 15) == 0) {
          const int rowg = m0 + wm * 128 + mt * 16 + qw * 4 + r;
          Z[((size_t)(bb * 16 + h)) * 4096 + (rowg & 4095)] = v;
        }
      }
    }
  }
}

// ---------------- KtQ partials: part[s][bh][e][d] = sum_{n in slab s} K[n,d]*Q[n,e] ----
#define KTS 136  // LDS row stride (ushorts): 272B = 16B-aligned, spreads frag-read banks
__global__ __launch_bounds__(256) void ktq_partial_kernel(const unsigned short* Qp,
                                                          const unsigned short* Kp,
                                                          float* part) {
  const int bh = blockIdx.x, b = bh >> 4, h = bh & 15;
  const int s = blockIdx.y;
  const unsigned short* Qh = Qp + (size_t)b * 4096 * 1024 + h * 64;
  const unsigned short* Kh = Kp + (size_t)b * 4096 * 1024 + h * 64;
  __shared__ unsigned short Kt[64 * KTS];
  __shared__ unsigned short Qt[64 * KTS];
  const int t = threadIdx.x, lane = t & 63, wave = t >> 6;
  floatx4 acc[4] = {};
  const int nlb = t >> 3;            // 0..31
  const int dblk = (t & 7) * 8;

  for (int c0 = s * 512; c0 < s * 512 + 512; c0 += 128) {
    __syncthreads();
#pragma unroll
    for (int it = 0; it < 4; ++it) {
      const int nl = it * 32 + nlb;
      const size_t goff = (size_t)(c0 + nl) * 1024 + dblk;
      short8 kv = *(const short8*)(Kh + goff);
      short8 qv = *(const short8*)(Qh + goff);
#pragma unroll
      for (int j = 0; j < 8; ++j) {
        Kt[(dblk + j) * KTS + nl] = (unsigned short)kv[j];
        Qt[(dblk + j) * KTS + nl] = (unsigned short)qv[j];
      }
    }
    __syncthreads();
#pragma unroll
    for (int ks = 0; ks < 4; ++ks) {
      const short8 a = *(const short8*)&Kt[(wave * 16 + (lane & 15)) * KTS + ks * 32 + (lane >> 4) * 8];
#pragma unroll
      for (int et = 0; et < 4; ++et) {
        const short8 bb = *(const short8*)&Qt[(et * 16 + (lane & 15)) * KTS + ks * 32 + (lane >> 4) * 8];
        acc[et] = __builtin_amdgcn_mfma_f32_16x16x32_bf16(a, bb, acc[et], 0, 0, 0);
      }
    }
  }
  float* outp = part + ((size_t)(s * 64 + bh)) * 4096;
#pragma unroll
  for (int et = 0; et < 4; ++et) {
    const int e = et * 16 + (lane & 15);
#pragma unroll
    for (int r = 0; r < 4; ++r) {
      const int d = wave * 16 + (lane >> 4) * 4 + r;
      outp[e * 64 + d] = acc[et][r];   // transposed store: [e][d]
    }
  }
}

// ---------------- reduce 8 slabs -> bf16 (KtQ)^T[e][d] ----------------
__global__ __launch_bounds__(256) void ktq_reduce_kernel(const float* __restrict__ part,
                                                         unsigned short* __restrict__ ktqt) {
  const int bh = blockIdx.x, t = threadIdx.x;
#pragma unroll
  for (int i = 0; i < 16; ++i) {
    const int idx = i * 256 + t;
    float s = 0.f;
#pragma unroll
    for (int sl = 0; sl < 8; ++sl) s += part[((size_t)(sl * 64 + bh)) * 4096 + idx];
    ktqt[(size_t)bh * 4096 + idx] = f2bf(s);
  }
}

// ---------------- U[b,n,h*64+e] = (sum_d V[n,d]*KtQ[d,e]) / (Z[b,h,n] + eps) ----------------
#define CTS 72  // kt_lds row stride: 144B = 16B-aligned, bank-spread
__global__ __launch_bounds__(256) void stagec_kernel(const unsigned short* Vp,
                                                     const unsigned short* ktqt,
                                                     const float* __restrict__ Z,
                                                     unsigned short* U) {
  const int bh = blockIdx.y, b = bh >> 4, h = bh & 15;
  const int n0 = blockIdx.x * 256;
  __shared__ unsigned short kt_lds[64 * CTS];
  __shared__ float zbuf[256];
  const int t = threadIdx.x, lane = t & 63, wave = t >> 6;

  {
    const unsigned short* src = ktqt + (size_t)bh * 4096;
    const int row = t >> 2, seg = (t & 3) * 16;
    *(short8*)&kt_lds[row * CTS + seg] = *(const short8*)(src + row * 64 + seg);
    *(short8*)&kt_lds[row * CTS + seg + 8] = *(const short8*)(src + row * 64 + seg + 8);
  }
  zbuf[t] = Z[(size_t)bh * 4096 + n0 + t];
  __syncthreads();

  const unsigned short* Vh = Vp + (size_t)b * 4096 * 1024 + h * 64;
  floatx4 acc[4][4] = {};
#pragma unroll
  for (int ks = 0; ks < 2; ++ks) {
    short8 bfr[4];
#pragma unroll
    for (int et = 0; et < 4; ++et)
      bfr[et] = *(const short8*)&kt_lds[(et * 16 + (lane & 15)) * CTS + ks * 32 + (lane >> 4) * 8];
#pragma unroll
    for (int mt = 0; mt < 4; ++mt) {
      const short8 a = *(const short8*)(Vh + (size_t)(n0 + wave * 64 + mt * 16 + (lane & 15)) * 1024 +
                                        ks * 32 + (lane >> 4) * 8);
#pragma unroll
      for (int et = 0; et < 4; ++et)
        acc[mt][et] = __builtin_amdgcn_mfma_f32_16x16x32_bf16(a, bfr[et], acc[mt][et], 0, 0, 0);
    }
  }
#pragma unroll
  for (int mt = 0; mt < 4; ++mt) {
#pragma unroll
    for (int r = 0; r < 4; ++r) {
      const int rl = wave * 64 + mt * 16 + (lane >> 4) * 4 + r;
      const float inv = 1.0f / (zbuf[rl] + 1e-9f);
#pragma unroll
      for (int et = 0; et < 4; ++et) {
        const int e = et * 16 + (lane & 15);
        U[((size_t)b * 4096 + n0 + rl) * 1024 + h * 64 + e] = f2bf(acc[mt][et][r] * inv);
      }
    }
  }
}

// ---------------- residual + LayerNorm ----------------
__global__ __launch_bounds__(256) void ln_kernel(const float* query, const unsigned short* attn,
                                                 const float* gamma, const float* beta, float* out) {
  const int row = blockIdx.x, t = threadIdx.x;
  const float* qrow = query + (size_t)row * 1024;
  const unsigned short* arow = attn + (size_t)row * 1024;
  const float4 qv = *(const float4*)(qrow + t * 4);
  const ushortx4 av = *(const ushortx4*)(arow + t * 4);
  float x0 = qv.x + bf2f(av.x), x1 = qv.y + bf2f(av.y);
  float x2 = qv.z + bf2f(av.z), x3 = qv.w + bf2f(av.w);
  float s = x0 + x1 + x2 + x3;
  float s2 = x0 * x0 + x1 * x1 + x2 * x2 + x3 * x3;
  for (int off = 32; off > 0; off >>= 1) {
    s += __shfl_down(s, off);
    s2 += __shfl_down(s2, off);
  }
  __shared__ float lred[8];
  if ((t & 63) == 0) { lred[(t >> 6) * 2] = s; lred[(t >> 6) * 2 + 1] = s2; }
  __syncthreads();
  s = lred[0] + lred[2] + lred[4] + lred[6];
  s2 = lred[1] + lred[3] + lred[5] + lred[7];
  const float mu = s * (1.f / 1024.f);
  const float var = s2 * (1.f / 1024.f) - mu * mu;
  const float rstd = rsqrtf(var + 1e-6f);
  float4 o;
  o.x = (x0 - mu) * rstd * gamma[t * 4 + 0] + beta[t * 4 + 0];
  o.y = (x1 - mu) * rstd * gamma[t * 4 + 1] + beta[t * 4 + 1];
  o.z = (x2 - mu) * rstd * gamma[t * 4 + 2] + beta[t * 4 + 2];
  o.w = (x3 - mu) * rstd * gamma[t * 4 + 3] + beta[t * 4 + 3];
  *(float4*)(out + (size_t)row * 1024 + t * 4) = o;
}

// ---------------- launch ----------------
extern "C" void kernel_launch(void* const* d_in, const int* in_sizes, int n_in,
                              void* d_out, int out_size, void* d_ws, size_t ws_size,
                              hipStream_t stream) {
  const float* query = (const float*)d_in[0];
  const float* key_  = (const float*)d_in[1];
  const float* value = (const float*)d_in[2];
  const float* Wq = (const float*)d_in[3];
  const float* bq = (const float*)d_in[4];
  const float* Wk = (const float*)d_in[5];
  const float* bk = (const float*)d_in[6];
  const float* Wv = (const float*)d_in[7];
  const float* bv = (const float*)d_in[8];
  const float* Wo = (const float*)d_in[9];
  const float* bo = (const float*)d_in[10];
  const float* gamma = (const float*)d_in[11];
  const float* beta = (const float*)d_in[12];
  float* out = (float*)d_out;

  char* ws = (char*)d_ws;
  // ws layout (~137.6 MiB peak):
  //   abf (32MB, rotating bf16 A; aliased by ktq partials (8MB) then U) | Qp | Kp | Vp
  //   | WT (8MB) | qsum (16KB) | ktqt (512KB) | Z (1MB).  attn aliases Qp.
  unsigned short* abf = (unsigned short*)(ws + 0);
  unsigned short* Qp = (unsigned short*)(ws + 33554432);
  unsigned short* Kp = (unsigned short*)(ws + 67108864);
  unsigned short* Vp = (unsigned short*)(ws + 100663296);
  unsigned short* WT = (unsigned short*)(ws + 134217728);
  float* qsumP = (float*)(ws + 142606336);
  unsigned short* ktqtP = (unsigned short*)(ws + 142606336 + 16384);
  float* Zp = (float*)(ws + 142606336 + 16384 + 524288);
  float* part = (float*)abf;   // 8MB; live only between ktq_partial and ktq_reduce
  unsigned short* U = abf;     // abf dead after gemmV / part dead after reduce
  unsigned short* attn = Qp;   // Qp dead after ktq_partial

  dim3 blk(256);
  dim3 gblk(512);

  W4 w4; w4.w[0] = Wq; w4.w[1] = Wk; w4.w[2] = Wv; w4.w[3] = Wo;
  wtrans_kernel<<<dim3(32, 32, 4), blk, 0, stream>>>(w4, WT);

  // zero the fused q_sum accumulator (16 KB)
  hipMemsetAsync(qsumP, 0, 64 * 64 * sizeof(float), stream);

  const int convGrid = 8192;      // 16384*1024 / (256*8)
  const int gemmGrid = 64 * 4;    // (M/256)*(N/256)

  conv_kernel<<<convGrid, blk, 0, stream>>>(query, abf);
  gemm_bt_kernel<<<gemmGrid, gblk, 0, stream>>>(abf, WT, bq, Qp, 1, 1, 0, qsumP, Zp,
                                                16384, 1024, 1024);

  conv_kernel<<<convGrid, blk, 0, stream>>>(key_, abf);
  gemm_bt_kernel<<<gemmGrid, gblk, 0, stream>>>(abf, WT + 1024 * 1024, bk, Kp, 1, 0, 1,
                                                qsumP, Zp, 16384, 1024, 1024);

  conv_kernel<<<convGrid, blk, 0, stream>>>(value, abf);
  gemm_bt_kernel<<<gemmGrid, gblk, 0, stream>>>(abf, WT + 2 * 1024 * 1024, bv, Vp, 0, 0, 0,
                                                qsumP, Zp, 16384, 1024, 1024);

  ktq_partial_kernel<<<dim3(64, 8), blk, 0, stream>>>(Qp, Kp, part);
  ktq_reduce_kernel<<<64, blk, 0, stream>>>(part, ktqtP);
  stagec_kernel<<<dim3(16, 64), blk, 0, stream>>>(Vp, ktqtP, Zp, U);

  gemm_bt_kernel<<<gemmGrid, gblk, 0, stream>>>(U, WT + 3 * 1024 * 1024, bo, attn, 0, 0, 0,
                                                qsumP, Zp, 16384, 1024, 1024);

  ln_kernel<<<16384, blk, 0, stream>>>(query, attn, gamma, beta, out);
}

// Round 3
// 481.896 us; speedup vs baseline: 1.3776x; 1.3776x over previous
//
#include <hip/hip_runtime.h>
#include <hip/hip_bf16.h>

// Problem: B=4, N=4096, D_MODEL=1024, H=16, DEPTH=64 (linear attention + LN)
// Pipeline: wtrans -> [conv->gemm]x3 (QKV; elu+1 on Q/K; fused q_sum on Q; fused Z on K)
//           -> ktq_partial -> ktq_reduce -> stagec -> gemm(Wo) -> LN
// R4: XOR-swizzled LDS + LDS-staged coalesced C store. R5: BK=64 (505 TF, MfmaUtil 18.7%).
// R6: 256^2/8-wave 4-phase K-tile schedule, counted vmcnt(6), raw s_barrier, setprio.
//     -> 690 TF, MfmaUtil 25%.
// R7: full A+B register double-buffer -> 224+ VGPR -> SCRATCH SPILLS (FETCH +14MB,
//     WRITE +17MB, 91us). Lesson: 256-VGPR cliff at 2 waves/SIMD.
// R8: A-only phase-ahead pipeline (af[2], 32 VGPR) + single-buffer B read at q0
//     (8 exposed reads/tile); counted lgkmcnt(4) drains only the previous phase's
//     reads; vmcnt(6)+barrier at q3 then prefetch next tile's A0. 4 barriers/tile.
//     ~220 VGPR total - no spills. Aux: ktq_partial float4 stores; stagec LDS-staged
//     coalesced U store (was 2B scalar global stores).

typedef __attribute__((ext_vector_type(8))) short short8;
typedef __attribute__((ext_vector_type(4))) float floatx4;
typedef __attribute__((ext_vector_type(4))) unsigned short ushortx4;
typedef __attribute__((ext_vector_type(8))) unsigned short ushortx8;

#define DEVINL __device__ __forceinline__

DEVINL unsigned short f2bf(float f) {
  unsigned int u = __builtin_bit_cast(unsigned int, f);
  u += 0x7fffu + ((u >> 16) & 1u);            // RNE
  return (unsigned short)(u >> 16);
}
DEVINL float bf2f(unsigned short h) {
  unsigned int u = ((unsigned int)h) << 16;
  return __builtin_bit_cast(float, u);
}
// async global->LDS, 16B per lane; LDS dest = wave-uniform base + lane*16
DEVINL void g2l16(const void* g, void* l) {
  __builtin_amdgcn_global_load_lds((const __attribute__((address_space(1))) void*)g,
                                   (__attribute__((address_space(3))) void*)l, 16, 0, 0);
}

// ---------------- fp32 -> bf16 elementwise (memory-bound) ----------------
__global__ __launch_bounds__(256) void conv_kernel(const float* __restrict__ in,
                                                   unsigned short* __restrict__ out) {
  const size_t i = ((size_t)blockIdx.x * 256 + threadIdx.x) * 8;
  const float4 a = *(const float4*)(in + i);
  const float4 b = *(const float4*)(in + i + 4);
  ushortx8 o;
  o[0] = f2bf(a.x); o[1] = f2bf(a.y); o[2] = f2bf(a.z); o[3] = f2bf(a.w);
  o[4] = f2bf(b.x); o[5] = f2bf(b.y); o[6] = f2bf(b.z); o[7] = f2bf(b.w);
  *(ushortx8*)(out + i) = o;
}

// ---------------- weight transpose + fp32->bf16 ----------------
struct W4 { const float* w[4]; };

__global__ __launch_bounds__(256) void wtrans_kernel(W4 wp, unsigned short* wt) {
  const int z = blockIdx.z;
  const float* W = wp.w[z];
  unsigned short* WT = wt + (size_t)z * 1024 * 1024;
  __shared__ float tile[32][33];
  const int bx = blockIdx.x, by = blockIdx.y;
  const int t = threadIdx.x, r = t >> 5, c = t & 31;
#pragma unroll
  for (int p = 0; p < 4; ++p)
    tile[p * 8 + r][c] = W[(size_t)(by * 32 + p * 8 + r) * 1024 + bx * 32 + c];
  __syncthreads();
#pragma unroll
  for (int p = 0; p < 4; ++p)
    WT[(size_t)(bx * 32 + p * 8 + r) * 1024 + by * 32 + c] = f2bf(tile[c][p * 8 + r]);
}

// ---------------- main GEMM: C[M,N] = A[M,K] * BT[N,K]^T + bias ----------------
// 256x256 tile, 8 waves (2m x 4n), per-wave 128x64 output, BK=64, 16 K-tiles.
// LDS: 2 buffers x (A 32KB + B 32KB) = 128KB. Swizzle: logical 8-elem col-chunk c of
// row r stored at physical chunk c ^ (r&7) (pre-swizzled global source, linear LDS dest).
// Stage units (64 rows each): U0=0-63, U1=64-127, U2=128-191, U3=192-255.
// Staging: q0 -> U1,U3(t+1) into lAn; q1,q2 -> B(t+2) into lBc; q3 -> U0,U2(t+2) into lAc.
// Reads: q0: B(t) 8 + A-phase1 4, lgkmcnt(4); q1/q2: A-phase 4, lgkmcnt(4);
//        q3: vmcnt(6)+barrier, A-phase0(t+1) 4 from lAn, lgkmcnt(4).
// MFMA(qp) consumes af[p&1] loaded one phase earlier. vmcnt(0) only before last tile.
__global__ __launch_bounds__(512, 2) void gemm_bt_kernel(const unsigned short* __restrict__ A,
                                                         const unsigned short* __restrict__ BT,
                                                         const float* __restrict__ bias,
                                                         unsigned short* __restrict__ C,
                                                         int act, int qsflag, int zflag,
                                                         float* qsum, float* Z,
                                                         int M, int N, int K) {
  const int mb = M >> 8;
  const int id = blockIdx.x;
  const int m0 = (id % mb) << 8;
  const int n0 = (id / mb) << 8;
  __shared__ unsigned short smem[65536];   // 128 KiB; k-loop: [buf][A 16384 | B 16384]
  const int t = threadIdx.x, lane = t & 63, wave = t >> 6;
  const int wm = wave >> 2, wn = wave & 3;
  const int srow = lane >> 3;                       // 0..7 row-in-chunk (staging)
  const int scol = ((lane & 7) ^ srow) * 8;         // pre-swizzled source col-chunk
  const int rl = lane & 15, qw = lane >> 4;
  const int NT = K >> 6;                            // 16

  floatx4 acc[8][4] = {};

  const unsigned short* Ag = A + (size_t)m0 * K;
  const unsigned short* Bg = BT + (size_t)n0 * K;

#define LA(c) (smem + (c) * 32768)
#define LB(c) (smem + (c) * 32768 + 16384)

  // stage this wave's 8-row chunk of a 64-row unit [R,R+64) at k-offset k0 into tile Lt
  auto STG = [&](unsigned short* Lt, const unsigned short* Gt, int R, int k0) {
    const int r0 = R + wave * 8;                    // wave-uniform
    g2l16(Gt + (size_t)(r0 + srow) * K + (k0 + scol), (void*)(Lt + r0 * 64));
  };
  // frag-read (logical k-chunk c of row r lives at physical chunk c ^ (r&7))
  auto FRAG = [&](const unsigned short* Lt, int row, int ks) -> short8 {
    return *(const short8*)&Lt[row * 64 + (((ks * 4 + qw) ^ (rl & 7)) * 8)];
  };

  // prologue: B(0) x4, A(0) x4, B(1) x4, U0U2(1) x2  -> vmcnt(6) leaves {B(1), U0U2(1)}
  STG(LB(0), Bg, 0, 0);    STG(LB(0), Bg, 64, 0);
  STG(LB(0), Bg, 128, 0);  STG(LB(0), Bg, 192, 0);
  STG(LA(0), Ag, 0, 0);    STG(LA(0), Ag, 64, 0);
  STG(LA(0), Ag, 128, 0);  STG(LA(0), Ag, 192, 0);
  STG(LB(1), Bg, 0, 64);   STG(LB(1), Bg, 64, 64);
  STG(LB(1), Bg, 128, 64); STG(LB(1), Bg, 192, 64);
  STG(LA(1), Ag, 0, 64);   STG(LA(1), Ag, 128, 64);
  asm volatile("s_waitcnt vmcnt(6)" ::: "memory");  // tile0 landed
  __builtin_amdgcn_s_barrier();

  short8 af[2][2][2];   // [phase parity][mt][ks] — A quadrant double-buffer
  short8 bfr[4][2];     // [nt][ks] — B frags of CURRENT tile (single-buffered)
  // preload af[0] = A-phase0 rows of tile 0
#pragma unroll
  for (int mt = 0; mt < 2; ++mt)
#pragma unroll
    for (int ks = 0; ks < 2; ++ks)
      af[0][mt][ks] = FRAG(LA(0), wm * 128 + mt * 16 + rl, ks);

  for (int tk = 0; tk < NT; ++tk) {
    unsigned short* lAc = LA(tk & 1);
    unsigned short* lBc = LB(tk & 1);
    unsigned short* lAn = LA((tk + 1) & 1);
    const int k1 = (tk + 1) << 6;
    const int k2 = (tk + 2) << 6;

    // ================= q0: MFMA phase0 (af[0], bfr) =================
    if (tk + 1 < NT) { STG(lAn, Ag, 64, k1); STG(lAn, Ag, 192, k1); }   // U1,U3(t+1)
#pragma unroll
    for (int nt = 0; nt < 4; ++nt)
#pragma unroll
      for (int ks = 0; ks < 2; ++ks)
        bfr[nt][ks] = FRAG(lBc, wn * 64 + nt * 16 + rl, ks);            // B(t): 8 reads
#pragma unroll
    for (int mt = 0; mt < 2; ++mt)
#pragma unroll
      for (int ks = 0; ks < 2; ++ks)
        af[1][mt][ks] = FRAG(lAc, wm * 128 + 32 + mt * 16 + rl, ks);    // phase1 A
    asm volatile("s_waitcnt lgkmcnt(4)" ::: "memory");                  // B + af[0] done
    __builtin_amdgcn_s_setprio(1);
#pragma unroll
    for (int ks = 0; ks < 2; ++ks)
#pragma unroll
      for (int mt = 0; mt < 2; ++mt)
#pragma unroll
        for (int nt = 0; nt < 4; ++nt)
          acc[mt][nt] = __builtin_amdgcn_mfma_f32_16x16x32_bf16(
              af[0][mt][ks], bfr[nt][ks], acc[mt][nt], 0, 0, 0);
    __builtin_amdgcn_s_setprio(0);
    __builtin_amdgcn_s_barrier();

    // ================= q1: MFMA phase1 (af[1]) =================
    if (tk + 2 < NT) { STG(lBc, Bg, 0, k2); STG(lBc, Bg, 64, k2); }     // B01(t+2)
#pragma unroll
    for (int mt = 0; mt < 2; ++mt)
#pragma unroll
      for (int ks = 0; ks < 2; ++ks)
        af[0][mt][ks] = FRAG(lAc, wm * 128 + 64 + mt * 16 + rl, ks);    // phase2 A
    asm volatile("s_waitcnt lgkmcnt(4)" ::: "memory");
    __builtin_amdgcn_s_setprio(1);
#pragma unroll
    for (int ks = 0; ks < 2; ++ks)
#pragma unroll
      for (int mt = 0; mt < 2; ++mt)
#pragma unroll
        for (int nt = 0; nt < 4; ++nt)
          acc[2 + mt][nt] = __builtin_amdgcn_mfma_f32_16x16x32_bf16(
              af[1][mt][ks], bfr[nt][ks], acc[2 + mt][nt], 0, 0, 0);
    __builtin_amdgcn_s_setprio(0);
    __builtin_amdgcn_s_barrier();

    // ================= q2: MFMA phase2 (af[0]) =================
    if (tk + 2 < NT) { STG(lBc, Bg, 128, k2); STG(lBc, Bg, 192, k2); }  // B23(t+2)
#pragma unroll
    for (int mt = 0; mt < 2; ++mt)
#pragma unroll
      for (int ks = 0; ks < 2; ++ks)
        af[1][mt][ks] = FRAG(lAc, wm * 128 + 96 + mt * 16 + rl, ks);    // phase3 A
    asm volatile("s_waitcnt lgkmcnt(4)" ::: "memory");
    __builtin_amdgcn_s_setprio(1);
#pragma unroll
    for (int ks = 0; ks < 2; ++ks)
#pragma unroll
      for (int mt = 0; mt < 2; ++mt)
#pragma unroll
        for (int nt = 0; nt < 4; ++nt)
          acc[4 + mt][nt] = __builtin_amdgcn_mfma_f32_16x16x32_bf16(
              af[0][mt][ks], bfr[nt][ks], acc[4 + mt][nt], 0, 0, 0);
    __builtin_amdgcn_s_setprio(0);
    __builtin_amdgcn_s_barrier();

    // ================= q3: MFMA phase3 (af[1]) =================
    if (tk + 2 < NT) { STG(lAc, Ag, 0, k2); STG(lAc, Ag, 128, k2); }    // U0,U2(t+2)
    if (tk + 1 < NT) {
      if (tk + 1 == NT - 1) asm volatile("s_waitcnt vmcnt(0)" ::: "memory");
      else                  asm volatile("s_waitcnt vmcnt(6)" ::: "memory");
    }
    __builtin_amdgcn_s_barrier();             // collectivize vmcnt before t+1 reads
    if (tk + 1 < NT) {
#pragma unroll
      for (int mt = 0; mt < 2; ++mt)
#pragma unroll
        for (int ks = 0; ks < 2; ++ks)
          af[0][mt][ks] = FRAG(lAn, wm * 128 + mt * 16 + rl, ks);       // phase0 A(t+1)
      asm volatile("s_waitcnt lgkmcnt(4)" ::: "memory");
    } else {
      asm volatile("s_waitcnt lgkmcnt(0)" ::: "memory");
    }
    __builtin_amdgcn_s_setprio(1);
#pragma unroll
    for (int ks = 0; ks < 2; ++ks)
#pragma unroll
      for (int mt = 0; mt < 2; ++mt)
#pragma unroll
        for (int nt = 0; nt < 4; ++nt)
          acc[6 + mt][nt] = __builtin_amdgcn_mfma_f32_16x16x32_bf16(
              af[1][mt][ks], bfr[nt][ks], acc[6 + mt][nt], 0, 0, 0);
    __builtin_amdgcn_s_setprio(0);
    // no trailing barrier: q0(t+1) staging targets are dead (proven by q1/q2 barriers),
    // and its B/A reads are gated by the q3 vmcnt+barrier above.
  }

  // ---- epilogue: C/D layout col=lane&15, row=(lane>>4)*4+reg ----
  // full 256x256 C tile staged in LDS (chunk ^ (row&15) swizzle), coalesced store.
  __syncthreads();   // per-wave lgkm/vm drain + block-wide fence before LDS reuse
  const int bb = m0 >> 12;   // 256-row tiles never straddle a batch
  float cs[4] = {0.f, 0.f, 0.f, 0.f};
  float zacc[8][4];
#pragma unroll
  for (int mt = 0; mt < 8; ++mt)
#pragma unroll
    for (int r = 0; r < 4; ++r) zacc[mt][r] = 0.f;

#pragma unroll
  for (int nt = 0; nt < 4; ++nt) {
    const int coll = wn * 64 + nt * 16 + rl;
    const int colg = n0 + coll;
    const float bv = bias[colg];
    float qsv = 0.f;
    if (zflag) qsv = qsum[(bb * 16 + (colg >> 6)) * 64 + (colg & 63)];
    const int chnk = wn * 4 + nt;                    // 16-col chunk index
#pragma unroll
    for (int mt = 0; mt < 8; ++mt) {
#pragma unroll
      for (int r = 0; r < 4; ++r) {
        const int rowl = wm * 128 + mt * 16 + qw * 4 + r;
        float v = acc[mt][nt][r] + bv;
        if (act) v = (v > 0.f) ? (v + 1.f) : __expf(v);   // elu(x)+1
        cs[nt] += v;
        if (zflag) zacc[mt][r] += v * qsv;
        smem[rowl * 256 + ((chnk ^ (rowl & 15)) * 16) + rl] = f2bf(v);
      }
    }
  }
  __syncthreads();
  // coalesced store: 256 rows x 512B; per row 32 threads x 16B
#pragma unroll
  for (int i = 0; i < 16; ++i) {
    const int idx = i * 512 + t;
    const int row = idx >> 5;
    const int seg = idx & 31;
    const int phys = (seg >> 1) ^ (row & 15);
    *(short8*)(C + (size_t)(m0 + row) * N + n0 + seg * 8) =
        *(const short8*)&smem[row * 256 + phys * 16 + (seg & 1) * 8];
  }

  if (qsflag) {
#pragma unroll
    for (int nt = 0; nt < 4; ++nt) {
      float v = cs[nt];
      v += __shfl_xor(v, 16);
      v += __shfl_xor(v, 32);   // lanes 0..15 hold this wave's 128-row column sum
      if (lane < 16) {
        const int colg = n0 + wn * 64 + nt * 16 + lane;
        atomicAdd(&qsum[(bb * 16 + (colg >> 6)) * 64 + (colg & 63)], v);
      }
    }
  }
  if (zflag) {
    // wave wn covers ALL 64 cols of head h: reduce over lane&15 -> full Z per row
    const int h = (n0 >> 6) + wn;
#pragma unroll
    for (int mt = 0; mt < 8; ++mt) {
#pragma unroll
      for (int r = 0; r < 4; ++r) {
        float v = zacc[mt][r];
        v += __shfl_xor(v, 1); v += __shfl_xor(v, 2);
        v += __shfl_xor(v, 4); v += __shfl_xor(v, 8);
        if ((lane & 15) == 0) {
          const int rowg = m0 + wm * 128 + mt * 16 + qw * 4 + r;
          Z[((size_t)(bb * 16 + h)) * 4096 + (rowg & 4095)] = v;
        }
      }
    }
  }
}

// ---------------- KtQ partials: part[s][bh][e][d] = sum_{n in slab s} K[n,d]*Q[n,e] ----
#define KTS 136  // LDS row stride (ushorts): 272B = 16B-aligned, spreads frag-read banks
__global__ __launch_bounds__(256) void ktq_partial_kernel(const unsigned short* Qp,
                                                          const unsigned short* Kp,
                                                          float* part) {
  const int bh = blockIdx.x, b = bh >> 4, h = bh & 15;
  const int s = blockIdx.y;
  const unsigned short* Qh = Qp + (size_t)b * 4096 * 1024 + h * 64;
  const unsigned short* Kh = Kp + (size_t)b * 4096 * 1024 + h * 64;
  __shared__ unsigned short Kt[64 * KTS];
  __shared__ unsigned short Qt[64 * KTS];
  const int t = threadIdx.x, lane = t & 63, wave = t >> 6;
  floatx4 acc[4] = {};
  const int nlb = t >> 3;            // 0..31
  const int dblk = (t & 7) * 8;

  for (int c0 = s * 512; c0 < s * 512 + 512; c0 += 128) {
    __syncthreads();
#pragma unroll
    for (int it = 0; it < 4; ++it) {
      const int nl = it * 32 + nlb;
      const size_t goff = (size_t)(c0 + nl) * 1024 + dblk;
      short8 kv = *(const short8*)(Kh + goff);
      short8 qv = *(const short8*)(Qh + goff);
#pragma unroll
      for (int j = 0; j < 8; ++j) {
        Kt[(dblk + j) * KTS + nl] = (unsigned short)kv[j];
        Qt[(dblk + j) * KTS + nl] = (unsigned short)qv[j];
      }
    }
    __syncthreads();
#pragma unroll
    for (int ks = 0; ks < 4; ++ks) {
      const short8 a = *(const short8*)&Kt[(wave * 16 + (lane & 15)) * KTS + ks * 32 + (lane >> 4) * 8];
#pragma unroll
      for (int et = 0; et < 4; ++et) {
        const short8 bb = *(const short8*)&Qt[(et * 16 + (lane & 15)) * KTS + ks * 32 + (lane >> 4) * 8];
        acc[et] = __builtin_amdgcn_mfma_f32_16x16x32_bf16(a, bb, acc[et], 0, 0, 0);
      }
    }
  }
  float* outp = part + ((size_t)(s * 64 + bh)) * 4096;
#pragma unroll
  for (int et = 0; et < 4; ++et) {
    const int e = et * 16 + (lane & 15);
    const int d0 = wave * 16 + (lane >> 4) * 4;
    *(floatx4*)&outp[e * 64 + d0] = acc[et];   // vectorized transposed store: [e][d]
  }
}

// ---------------- reduce 8 slabs -> bf16 (KtQ)^T[e][d] ----------------
__global__ __launch_bounds__(256) void ktq_reduce_kernel(const float* __restrict__ part,
                                                         unsigned short* __restrict__ ktqt) {
  const int bh = blockIdx.x, t = threadIdx.x;
#pragma unroll
  for (int i = 0; i < 16; ++i) {
    const int idx = i * 256 + t;
    float s = 0.f;
#pragma unroll
    for (int sl = 0; sl < 8; ++sl) s += part[((size_t)(sl * 64 + bh)) * 4096 + idx];
    ktqt[(size_t)bh * 4096 + idx] = f2bf(s);
  }
}

// ---------------- U[b,n,h*64+e] = (sum_d V[n,d]*KtQ[d,e]) / (Z[b,h,n] + eps) ----------------
#define CTS 72  // kt_lds row stride: 144B = 16B-aligned, bank-spread
__global__ __launch_bounds__(256) void stagec_kernel(const unsigned short* Vp,
                                                     const unsigned short* ktqt,
                                                     const float* __restrict__ Z,
                                                     unsigned short* U) {
  const int bh = blockIdx.y, b = bh >> 4, h = bh & 15;
  const int n0 = blockIdx.x * 256;
  __shared__ unsigned short kt_lds[64 * CTS];
  __shared__ float zbuf[256];
  __shared__ unsigned short ustage[256 * 64];   // 32KB staged output tile
  const int t = threadIdx.x, lane = t & 63, wave = t >> 6;

  {
    const unsigned short* src = ktqt + (size_t)bh * 4096;
    const int row = t >> 2, seg = (t & 3) * 16;
    *(short8*)&kt_lds[row * CTS + seg] = *(const short8*)(src + row * 64 + seg);
    *(short8*)&kt_lds[row * CTS + seg + 8] = *(const short8*)(src + row * 64 + seg + 8);
  }
  zbuf[t] = Z[(size_t)bh * 4096 + n0 + t];
  __syncthreads();

  const unsigned short* Vh = Vp + (size_t)b * 4096 * 1024 + h * 64;
  floatx4 acc[4][4] = {};
#pragma unroll
  for (int ks = 0; ks < 2; ++ks) {
    short8 bfr[4];
#pragma unroll
    for (int et = 0; et < 4; ++et)
      bfr[et] = *(const short8*)&kt_lds[(et * 16 + (lane & 15)) * CTS + ks * 32 + (lane >> 4) * 8];
#pragma unroll
    for (int mt = 0; mt < 4; ++mt) {
      const short8 a = *(const short8*)(Vh + (size_t)(n0 + wave * 64 + mt * 16 + (lane & 15)) * 1024 +
                                        ks * 32 + (lane >> 4) * 8);
#pragma unroll
      for (int et = 0; et < 4; ++et)
        acc[mt][et] = __builtin_amdgcn_mfma_f32_16x16x32_bf16(a, bfr[et], acc[mt][et], 0, 0, 0);
    }
  }
#pragma unroll
  for (int mt = 0; mt < 4; ++mt) {
#pragma unroll
    for (int r = 0; r < 4; ++r) {
      const int rl = wave * 64 + mt * 16 + (lane >> 4) * 4 + r;
      const float inv = 1.0f / (zbuf[rl] + 1e-9f);
#pragma unroll
      for (int et = 0; et < 4; ++et)
        ustage[rl * 64 + et * 16 + (lane & 15)] = f2bf(acc[mt][et][r] * inv);
    }
  }
  __syncthreads();
  // coalesced store: 256 rows x 128B; 8 threads x 16B per row
  {
    const int srow = t >> 3, scol = (t & 7) * 8;
#pragma unroll
    for (int i = 0; i < 8; ++i) {
      const int row = i * 32 + srow;
      *(short8*)(U + ((size_t)b * 4096 + n0 + row) * 1024 + h * 64 + scol) =
          *(const short8*)&ustage[row * 64 + scol];
    }
  }
}

// ---------------- residual + LayerNorm ----------------
__global__ __launch_bounds__(256) void ln_kernel(const float* query, const unsigned short* attn,
                                                 const float* gamma, const float* beta, float* out) {
  const int row = blockIdx.x, t = threadIdx.x;
  const float* qrow = query + (size_t)row * 1024;
  const unsigned short* arow = attn + (size_t)row * 1024;
  const float4 qv = *(const float4*)(qrow + t * 4);
  const ushortx4 av = *(const ushortx4*)(arow + t * 4);
  float x0 = qv.x + bf2f(av.x), x1 = qv.y + bf2f(av.y);
  float x2 = qv.z + bf2f(av.z), x3 = qv.w + bf2f(av.w);
  float s = x0 + x1 + x2 + x3;
  float s2 = x0 * x0 + x1 * x1 + x2 * x2 + x3 * x3;
  for (int off = 32; off > 0; off >>= 1) {
    s += __shfl_down(s, off);
    s2 += __shfl_down(s2, off);
  }
  __shared__ float lred[8];
  if ((t & 63) == 0) { lred[(t >> 6) * 2] = s; lred[(t >> 6) * 2 + 1] = s2; }
  __syncthreads();
  s = lred[0] + lred[2] + lred[4] + lred[6];
  s2 = lred[1] + lred[3] + lred[5] + lred[7];
  const float mu = s * (1.f / 1024.f);
  const float var = s2 * (1.f / 1024.f) - mu * mu;
  const float rstd = rsqrtf(var + 1e-6f);
  float4 o;
  o.x = (x0 - mu) * rstd * gamma[t * 4 + 0] + beta[t * 4 + 0];
  o.y = (x1 - mu) * rstd * gamma[t * 4 + 1] + beta[t * 4 + 1];
  o.z = (x2 - mu) * rstd * gamma[t * 4 + 2] + beta[t * 4 + 2];
  o.w = (x3 - mu) * rstd * gamma[t * 4 + 3] + beta[t * 4 + 3];
  *(float4*)(out + (size_t)row * 1024 + t * 4) = o;
}

// ---------------- launch ----------------
extern "C" void kernel_launch(void* const* d_in, const int* in_sizes, int n_in,
                              void* d_out, int out_size, void* d_ws, size_t ws_size,
                              hipStream_t stream) {
  const float* query = (const float*)d_in[0];
  const float* key_  = (const float*)d_in[1];
  const float* value = (const float*)d_in[2];
  const float* Wq = (const float*)d_in[3];
  const float* bq = (const float*)d_in[4];
  const float* Wk = (const float*)d_in[5];
  const float* bk = (const float*)d_in[6];
  const float* Wv = (const float*)d_in[7];
  const float* bv = (const float*)d_in[8];
  const float* Wo = (const float*)d_in[9];
  const float* bo = (const float*)d_in[10];
  const float* gamma = (const float*)d_in[11];
  const float* beta = (const float*)d_in[12];
  float* out = (float*)d_out;

  char* ws = (char*)d_ws;
  // ws layout (~137.6 MiB peak):
  //   abf (32MB, rotating bf16 A; aliased by ktq partials (8MB) then U) | Qp | Kp | Vp
  //   | WT (8MB) | qsum (16KB) | ktqt (512KB) | Z (1MB).  attn aliases Qp.
  unsigned short* abf = (unsigned short*)(ws + 0);
  unsigned short* Qp = (unsigned short*)(ws + 33554432);
  unsigned short* Kp = (unsigned short*)(ws + 67108864);
  unsigned short* Vp = (unsigned short*)(ws + 100663296);
  unsigned short* WT = (unsigned short*)(ws + 134217728);
  float* qsumP = (float*)(ws + 142606336);
  unsigned short* ktqtP = (unsigned short*)(ws + 142606336 + 16384);
  float* Zp = (float*)(ws + 142606336 + 16384 + 524288);
  float* part = (float*)abf;   // 8MB; live only between ktq_partial and ktq_reduce
  unsigned short* U = abf;     // abf dead after gemmV / part dead after reduce
  unsigned short* attn = Qp;   // Qp dead after ktq_partial

  dim3 blk(256);
  dim3 gblk(512);

  W4 w4; w4.w[0] = Wq; w4.w[1] = Wk; w4.w[2] = Wv; w4.w[3] = Wo;
  wtrans_kernel<<<dim3(32, 32, 4), blk, 0, stream>>>(w4, WT);

  // zero the fused q_sum accumulator (16 KB)
  hipMemsetAsync(qsumP, 0, 64 * 64 * sizeof(float), stream);

  const int convGrid = 8192;      // 16384*1024 / (256*8)
  const int gemmGrid = 64 * 4;    // (M/256)*(N/256)

  conv_kernel<<<convGrid, blk, 0, stream>>>(query, abf);
  gemm_bt_kernel<<<gemmGrid, gblk, 0, stream>>>(abf, WT, bq, Qp, 1, 1, 0, qsumP, Zp,
                                                16384, 1024, 1024);

  conv_kernel<<<convGrid, blk, 0, stream>>>(key_, abf);
  gemm_bt_kernel<<<gemmGrid, gblk, 0, stream>>>(abf, WT + 1024 * 1024, bk, Kp, 1, 0, 1,
                                                qsumP, Zp, 16384, 1024, 1024);

  conv_kernel<<<convGrid, blk, 0, stream>>>(value, abf);
  gemm_bt_kernel<<<gemmGrid, gblk, 0, stream>>>(abf, WT + 2 * 1024 * 1024, bv, Vp, 0, 0, 0,
                                                qsumP, Zp, 16384, 1024, 1024);

  ktq_partial_kernel<<<dim3(64, 8), blk, 0, stream>>>(Qp, Kp, part);
  ktq_reduce_kernel<<<64, blk, 0, stream>>>(part, ktqtP);
  stagec_kernel<<<dim3(16, 64), blk, 0, stream>>>(Vp, ktqtP, Zp, U);

  gemm_bt_kernel<<<gemmGrid, gblk, 0, stream>>>(U, WT + 3 * 1024 * 1024, bo, attn, 0, 0, 0,
                                                qsumP, Zp, 16384, 1024, 1024);

  ln_kernel<<<16384, blk, 0, stream>>>(query, attn, gamma, beta, out);
}